// Round 1
// baseline (119.019 us; speedup 1.0000x reference)
//
#include <hip/hip_runtime.h>

// Steerable_Encoder: separable Gaussian KDE onto a 128x128 grid.
// FM[i,j,c] = sum_n A[i,n]*B[j,n]*EY[n,c], A/B = 1-D Gaussians (separable!),
// EY = [1, Y0, Y1]. Then out[0,c,j,i] = {FM0, FM1/FM0, FM2/FM0}.

#define NXA 128
#define NYA 128
#define NG  (NXA * NYA)      // 16384 grid points
#define NC  20000            // context points
#define NSLICE 64            // ctx slices (split-K across blocks)
#define SLICE  313           // ceil(20000/64)
#define CHUNK  64            // ctx chunk staged in LDS
#define TILE   64            // block covers 64x64 grid tile

#define STEP  (20.0f / 127.0f)
#define KNEG  (-0.72134752044448170368f)   // -0.5 * log2(e)

__device__ __forceinline__ float fast_exp2(float x) {
    return __builtin_amdgcn_exp2f(x);      // v_exp_f32
}

// mode 0: write per-slice partials to dst[slice][g*3+c] (no atomics)
// mode 1: atomicAdd directly into out layout dst[c*NG + j*128 + i]
__global__ __launch_bounds__(256) void k_accum(const float* __restrict__ X,
                                               const float* __restrict__ Y,
                                               float* __restrict__ dst,
                                               int mode) {
    __shared__ float As[CHUNK * TILE];     // A[n_local][i_local]
    __shared__ float Bs[CHUNK * TILE];     // B[n_local][j_local]
    __shared__ float Ys[CHUNK * 2];        // Y[n_local][0..1]

    const int t  = threadIdx.x;
    const int tx = t & 15;                 // j-group (4 j's each)
    const int ty = t >> 4;                 // i-group (4 i's each)
    const int pos = blockIdx.x;            // 0..3 tile position
    const int tI = (pos >> 1) * TILE;
    const int tJ = (pos & 1) * TILE;
    const int slice = blockIdx.y;
    const int n0   = slice * SLICE;
    const int nEnd = (n0 + SLICE < NC) ? (n0 + SLICE) : NC;

    float accW[16], accP[16], accQ[16];
#pragma unroll
    for (int k = 0; k < 16; ++k) { accW[k] = 0.f; accP[k] = 0.f; accQ[k] = 0.f; }

    for (int c0 = n0; c0 < nEnd; c0 += CHUNK) {
        __syncthreads();
        // --- stage A,B tiles: 64 ctx x 64 grid each; 16 elems/thread ---
#pragma unroll
        for (int k = 0; k < 16; ++k) {
            int l  = k * 256 + t;
            int nl = l >> 6;               // wave-uniform: scalar X load
            int ii = l & 63;               // lane id: coalesced LDS write
            int n  = c0 + nl;
            float a = 0.f, b = 0.f;
            if (n < nEnd) {
                float x0 = X[2 * n];
                float x1 = X[2 * n + 1];
                float gx = -10.f + (float)(tI + ii) * STEP;  // xs[i]
                float gy =  10.f - (float)(tJ + ii) * STEP;  // ys[j] (reversed)
                float dx = gx - x0;
                float dy = gy - x1;
                a = fast_exp2(dx * dx * KNEG);
                b = fast_exp2(dy * dy * KNEG);
            }
            As[nl * TILE + ii] = a;
            Bs[nl * TILE + ii] = b;
        }
        if (t < 2 * CHUNK) {
            int n = c0 + (t >> 1);
            Ys[t] = (n < nEnd) ? Y[2 * n + (t & 1)] : 0.f;
        }
        __syncthreads();

        int cnt = nEnd - c0; if (cnt > CHUNK) cnt = CHUNK;
        for (int n = 0; n < cnt; ++n) {
            const float4 a4 = *(const float4*)(As + n * TILE + ty * 4);
            const float4 b4 = *(const float4*)(Bs + n * TILE + tx * 4);
            const float y0 = Ys[2 * n];
            const float y1 = Ys[2 * n + 1];
            float av[4] = {a4.x, a4.y, a4.z, a4.w};
            float bv[4] = {b4.x, b4.y, b4.z, b4.w};
#pragma unroll
            for (int di = 0; di < 4; ++di)
#pragma unroll
                for (int dj = 0; dj < 4; ++dj) {
                    int k = di * 4 + dj;
                    float w = av[di] * bv[dj];
                    accW[k] += w;
                    accP[k] = fmaf(w, y0, accP[k]);
                    accQ[k] = fmaf(w, y1, accQ[k]);
                }
        }
    }

    if (mode == 0) {
        float* p = dst + (size_t)slice * (NG * 3);
#pragma unroll
        for (int di = 0; di < 4; ++di) {
            int gi = tI + ty * 4 + di;
#pragma unroll
            for (int dj = 0; dj < 4; ++dj) {
                int gj = tJ + tx * 4 + dj;
                int g  = gi * NYA + gj;
                int k  = di * 4 + dj;
                p[g * 3 + 0] = accW[k];
                p[g * 3 + 1] = accP[k];
                p[g * 3 + 2] = accQ[k];
            }
        }
    } else {
#pragma unroll
        for (int di = 0; di < 4; ++di) {
            int gi = tI + ty * 4 + di;       // i (x index)
#pragma unroll
            for (int dj = 0; dj < 4; ++dj) {
                int gj = tJ + tx * 4 + dj;   // j (y index)
                int k  = di * 4 + dj;
                int o  = gj * NXA + gi;      // out[c][j][i]
                atomicAdd(dst + 0 * NG + o, accW[k]);
                atomicAdd(dst + 1 * NG + o, accP[k]);
                atomicAdd(dst + 2 * NG + o, accQ[k]);
            }
        }
    }
}

// partial path: reduce NSLICE partials, normalize, transpose-write
__global__ __launch_bounds__(256) void k_reduce_norm(const float* __restrict__ fm,
                                                     float* __restrict__ out) {
    int g = blockIdx.x * 256 + threadIdx.x;
    if (g >= NG) return;
    float w = 0.f, p = 0.f, q = 0.f;
    for (int s = 0; s < NSLICE; ++s) {
        const float* src = fm + (size_t)s * (NG * 3) + g * 3;  // coalesced
        w += src[0]; p += src[1]; q += src[2];
    }
    int ix = g >> 7;       // i (x index)
    int iy = g & 127;      // j (y index)
    int o  = iy * NXA + ix;
    float inv = 1.f / w;
    out[o]          = w;
    out[NG + o]     = p * inv;
    out[2 * NG + o] = q * inv;
}

// atomic path: normalize in place (density already in channel 0)
__global__ __launch_bounds__(256) void k_norm_inplace(float* __restrict__ out) {
    int t = blockIdx.x * 256 + threadIdx.x;
    if (t >= NG) return;
    float inv = 1.f / out[t];
    out[NG + t]     *= inv;
    out[2 * NG + t] *= inv;
}

extern "C" void kernel_launch(void* const* d_in, const int* in_sizes, int n_in,
                              void* d_out, int out_size, void* d_ws, size_t ws_size,
                              hipStream_t stream) {
    const float* X = (const float*)d_in[0];
    const float* Y = (const float*)d_in[1];
    float* out = (float*)d_out;
    const size_t partial_bytes = (size_t)NSLICE * NG * 3 * sizeof(float);  // ~12.6 MB
    dim3 grid(4, NSLICE);
    if (ws_size >= partial_bytes) {
        float* fm = (float*)d_ws;
        k_accum<<<grid, 256, 0, stream>>>(X, Y, fm, 0);
        k_reduce_norm<<<(NG + 255) / 256, 256, 0, stream>>>(fm, out);
    } else {
        hipMemsetAsync(d_out, 0, (size_t)out_size * sizeof(float), stream);
        k_accum<<<grid, 256, 0, stream>>>(X, Y, out, 1);
        k_norm_inplace<<<(NG + 255) / 256, 256, 0, stream>>>(out);
    }
}

// Round 2
// 113.689 us; speedup vs baseline: 1.0469x; 1.0469x over previous
//
#include <hip/hip_runtime.h>

// Steerable_Encoder: separable Gaussian KDE onto a 128x128 grid.
// FM[i,j,c] = sum_n A[i,n]*B[j,n]*EY[n,c], A/B = 1-D Gaussians (separable),
// EY = [1, Y0, Y1]. Then out[0,c,j,i] = {FM0, FM1/FM0, FM2/FM0}.
//
// R1 post-mortem: k_accum at 256 blocks = 1 block/CU = 10% occupancy,
// VALUBusy 31%. Fix: split ctx into up to 256 slices (1024 blocks,
// 4 blocks/CU by LDS=33KB), planar partials [c][slice][g] in d_ws.

#define NXA 128
#define NYA 128
#define NG  (NXA * NYA)      // 16384 grid points
#define NC  20000            // context points
#define CHUNK  64            // ctx chunk staged in LDS
#define TILE   64            // block covers 64x64 grid tile

#define STEP  (20.0f / 127.0f)
#define KNEG  (-0.72134752044448170368f)   // -0.5 * log2(e)

__device__ __forceinline__ float fast_exp2(float x) {
    return __builtin_amdgcn_exp2f(x);      // v_exp_f32
}

// mode 0: partials fm[c][slice][g], g = i*NYA + j  (no atomics)
// mode 1: atomicAdd directly into out layout dst[c*NG + j*128 + i]
__global__ __launch_bounds__(256) void k_accum(const float* __restrict__ X,
                                               const float* __restrict__ Y,
                                               float* __restrict__ dst,
                                               int nslice, int slice_len,
                                               int mode) {
    __shared__ float As[CHUNK * TILE];     // A[n_local][i_local]
    __shared__ float Bs[CHUNK * TILE];     // B[n_local][j_local]
    __shared__ float Ys[CHUNK * 2];        // Y[n_local][0..1]

    const int t  = threadIdx.x;
    const int tx = t & 15;                 // j-group (4 j's each)
    const int ty = t >> 4;                 // i-group (4 i's each)
    const int pos = blockIdx.x;            // 0..3 tile position
    const int tI = (pos >> 1) * TILE;
    const int tJ = (pos & 1) * TILE;
    const int slice = blockIdx.y;
    const int n0   = slice * slice_len;
    int nEnd = n0 + slice_len;
    if (nEnd > NC) nEnd = NC;

    float accW[16], accP[16], accQ[16];
#pragma unroll
    for (int k = 0; k < 16; ++k) { accW[k] = 0.f; accP[k] = 0.f; accQ[k] = 0.f; }

    for (int c0 = n0; c0 < nEnd; c0 += CHUNK) {
        __syncthreads();
        // --- stage A,B tiles: 64 ctx x 64 grid each; 16 elems/thread ---
#pragma unroll
        for (int k = 0; k < 16; ++k) {
            int l  = k * 256 + t;
            int nl = l >> 6;               // wave-uniform: scalar-ish X load
            int ii = l & 63;               // lane id: coalesced LDS write
            int n  = c0 + nl;
            float a = 0.f, b = 0.f;
            if (n < nEnd) {
                float x0 = X[2 * n];
                float x1 = X[2 * n + 1];
                float gx = -10.f + (float)(tI + ii) * STEP;  // xs[i]
                float gy =  10.f - (float)(tJ + ii) * STEP;  // ys[j] (reversed)
                float dx = gx - x0;
                float dy = gy - x1;
                a = fast_exp2(dx * dx * KNEG);
                b = fast_exp2(dy * dy * KNEG);
            }
            As[nl * TILE + ii] = a;
            Bs[nl * TILE + ii] = b;
        }
        if (t < 2 * CHUNK) {
            int n = c0 + (t >> 1);
            Ys[t] = (n < nEnd) ? Y[2 * n + (t & 1)] : 0.f;
        }
        __syncthreads();

        int cnt = nEnd - c0; if (cnt > CHUNK) cnt = CHUNK;
#pragma unroll 2
        for (int n = 0; n < cnt; ++n) {
            const float4 a4 = *(const float4*)(As + n * TILE + ty * 4);
            const float4 b4 = *(const float4*)(Bs + n * TILE + tx * 4);
            const float2 y2 = *(const float2*)(Ys + 2 * n);
            float av[4] = {a4.x, a4.y, a4.z, a4.w};
            float bv[4] = {b4.x, b4.y, b4.z, b4.w};
#pragma unroll
            for (int di = 0; di < 4; ++di)
#pragma unroll
                for (int dj = 0; dj < 4; ++dj) {
                    int k = di * 4 + dj;
                    float w = av[di] * bv[dj];
                    accW[k] += w;
                    accP[k] = fmaf(w, y2.x, accP[k]);
                    accQ[k] = fmaf(w, y2.y, accQ[k]);
                }
        }
    }

    if (mode == 0) {
        const size_t plane = (size_t)nslice * NG;
        float* pw = dst + (size_t)slice * NG;
#pragma unroll
        for (int di = 0; di < 4; ++di) {
            int gi = tI + ty * 4 + di;
            int g  = gi * NYA + tJ + tx * 4;     // 4 consecutive g's
            int k  = di * 4;
            float4 w4 = make_float4(accW[k], accW[k+1], accW[k+2], accW[k+3]);
            float4 p4 = make_float4(accP[k], accP[k+1], accP[k+2], accP[k+3]);
            float4 q4 = make_float4(accQ[k], accQ[k+1], accQ[k+2], accQ[k+3]);
            *(float4*)(pw + g)             = w4;
            *(float4*)(pw + plane + g)     = p4;
            *(float4*)(pw + 2 * plane + g) = q4;
        }
    } else {
#pragma unroll
        for (int di = 0; di < 4; ++di) {
            int gi = tI + ty * 4 + di;       // i (x index)
#pragma unroll
            for (int dj = 0; dj < 4; ++dj) {
                int gj = tJ + tx * 4 + dj;   // j (y index)
                int k  = di * 4 + dj;
                int o  = gj * NXA + gi;      // out[c][j][i]
                atomicAdd(dst + 0 * NG + o, accW[k]);
                atomicAdd(dst + 1 * NG + o, accP[k]);
                atomicAdd(dst + 2 * NG + o, accQ[k]);
            }
        }
    }
}

// reduce nslice partials, normalize, transpose-write.
// block = 256 thr: 64 grid points x 4 slice-groups, LDS combine.
__global__ __launch_bounds__(256) void k_reduce_norm(const float* __restrict__ fm,
                                                     float* __restrict__ out,
                                                     int nslice) {
    __shared__ float sW[256], sP[256], sQ[256];
    const int gl = threadIdx.x & 63;
    const int sg = threadIdx.x >> 6;
    const int g  = blockIdx.x * 64 + gl;
    const size_t plane = (size_t)nslice * NG;
    const int per = (nslice + 3) >> 2;
    int s0 = sg * per;
    int s1 = s0 + per; if (s1 > nslice) s1 = nslice;
    float w = 0.f, p = 0.f, q = 0.f;
    for (int s = s0; s < s1; ++s) {
        const float* base = fm + (size_t)s * NG + g;     // coalesced across gl
        w += base[0];
        p += base[plane];
        q += base[2 * plane];
    }
    sW[threadIdx.x] = w; sP[threadIdx.x] = p; sQ[threadIdx.x] = q;
    __syncthreads();
    if (sg == 0) {
        w = sW[gl] + sW[64 + gl] + sW[128 + gl] + sW[192 + gl];
        p = sP[gl] + sP[64 + gl] + sP[128 + gl] + sP[192 + gl];
        q = sQ[gl] + sQ[64 + gl] + sQ[128 + gl] + sQ[192 + gl];
        int ix = g >> 7;        // i (x index)
        int iy = g & 127;       // j (y index)
        int o  = iy * NXA + ix;
        float inv = 1.f / w;
        out[o]          = w;
        out[NG + o]     = p * inv;
        out[2 * NG + o] = q * inv;
    }
}

// atomic path: normalize in place (density already in channel 0)
__global__ __launch_bounds__(256) void k_norm_inplace(float* __restrict__ out) {
    int t = blockIdx.x * 256 + threadIdx.x;
    if (t >= NG) return;
    float inv = 1.f / out[t];
    out[NG + t]     *= inv;
    out[2 * NG + t] *= inv;
}

extern "C" void kernel_launch(void* const* d_in, const int* in_sizes, int n_in,
                              void* d_out, int out_size, void* d_ws, size_t ws_size,
                              hipStream_t stream) {
    const float* X = (const float*)d_in[0];
    const float* Y = (const float*)d_in[1];
    float* out = (float*)d_out;
    const size_t per_slice = (size_t)NG * 3 * sizeof(float);   // 196.6 KB

    int nslice = 0;
    if      (ws_size >= 256 * per_slice) nslice = 256;  // 50.3 MB
    else if (ws_size >= 128 * per_slice) nslice = 128;  // 25.2 MB
    else if (ws_size >=  64 * per_slice) nslice = 64;   // 12.6 MB

    if (nslice > 0) {
        int slice_len = (NC + nslice - 1) / nslice;
        float* fm = (float*)d_ws;
        dim3 grid(4, nslice);
        k_accum<<<grid, 256, 0, stream>>>(X, Y, fm, nslice, slice_len, 0);
        k_reduce_norm<<<NG / 64, 256, 0, stream>>>(fm, out, nslice);
    } else {
        hipMemsetAsync(d_out, 0, (size_t)out_size * sizeof(float), stream);
        dim3 grid(4, 64);
        k_accum<<<grid, 256, 0, stream>>>(X, Y, out, 64, (NC + 63) / 64, 1);
        k_norm_inplace<<<(NG + 255) / 256, 256, 0, stream>>>(out);
    }
}

// Round 3
// 102.199 us; speedup vs baseline: 1.1646x; 1.1124x over previous
//
#include <hip/hip_runtime.h>

// Steerable_Encoder: separable Gaussian KDE onto a 128x128 grid.
// FM[i,j,c] = sum_n A[i,n]*B[j,n]*EY[n,c], A/B = 1-D Gaussians (separable),
// EY = [1, Y0, Y1]. out[0,c,j,i] = {FM0, FM1/FM0, FM2/FM0}.
//
// R2 post-mortem: both kernels < 45 us (below harness ws-poison fills);
// ~60 us kernel total remains. R3: packed fp32 (v_pk_fma_f32) inner loop,
// j-major partials + float4 reduce with coalesced final writes.

#define NXA 128
#define NYA 128
#define NG  (NXA * NYA)      // 16384 grid points
#define NC  20000            // context points
#define CHUNK  64            // ctx chunk staged in LDS
#define TILE   64            // block covers 64x64 grid tile

#define STEP  (20.0f / 127.0f)
#define KNEG  (-0.72134752044448170368f)   // -0.5 * log2(e)

typedef float v2f __attribute__((ext_vector_type(2)));
typedef float v4f __attribute__((ext_vector_type(4)));

__device__ __forceinline__ float fast_exp2(float x) {
    return __builtin_amdgcn_exp2f(x);      // v_exp_f32
}

// mode 0: partials fm[c][slice][g'], g' = gj*NXA + gi (j-major -> coalesced out)
// mode 1: atomicAdd directly into out layout dst[c*NG + gj*128 + gi]
__global__ __launch_bounds__(256, 4) void k_accum(const float* __restrict__ X,
                                                  const float* __restrict__ Y,
                                                  float* __restrict__ dst,
                                                  int nslice, int slice_len,
                                                  int mode) {
    __shared__ float As[CHUNK * TILE];     // A[n_local][i_local]
    __shared__ float Bs[CHUNK * TILE];     // B[n_local][j_local]
    __shared__ float Ys[CHUNK * 2];        // Y[n_local][0..1]

    const int t  = threadIdx.x;
    const int tx = t & 15;                 // i-group: 4 consecutive gi
    const int ty = t >> 4;                 // j-group: 4 consecutive gj
    const int pos = blockIdx.x;            // 0..3 tile position
    const int tI = (pos >> 1) * TILE;
    const int tJ = (pos & 1) * TILE;
    const int slice = blockIdx.y;
    const int n0   = slice * slice_len;
    int nEnd = n0 + slice_len;
    if (nEnd > NC) nEnd = NC;

    v2f accW[8];     // [di*2 + djpair] : W for points (di, 2*djp), (di, 2*djp+1)
    v2f accPQ[16];   // [di*4 + dj] : (P,Q) for point (di,dj)
#pragma unroll
    for (int k = 0; k < 8; ++k)  accW[k]  = (v2f)(0.f);
#pragma unroll
    for (int k = 0; k < 16; ++k) accPQ[k] = (v2f)(0.f);

    for (int c0 = n0; c0 < nEnd; c0 += CHUNK) {
        __syncthreads();
        // --- stage A,B tiles: 64 ctx x 64 grid each; 16 elems/thread ---
#pragma unroll
        for (int k = 0; k < 16; ++k) {
            int l  = k * 256 + t;
            int nl = l >> 6;
            int ii = l & 63;
            int n  = c0 + nl;
            float a = 0.f, b = 0.f;
            if (n < nEnd) {
                float x0 = X[2 * n];
                float x1 = X[2 * n + 1];
                float gx = -10.f + (float)(tI + ii) * STEP;  // xs[i]
                float gy =  10.f - (float)(tJ + ii) * STEP;  // ys[j] (reversed)
                float dx = gx - x0;
                float dy = gy - x1;
                a = fast_exp2(dx * dx * KNEG);
                b = fast_exp2(dy * dy * KNEG);
            }
            As[nl * TILE + ii] = a;
            Bs[nl * TILE + ii] = b;
        }
        if (t < 2 * CHUNK) {
            int n = c0 + (t >> 1);
            Ys[t] = (n < nEnd) ? Y[2 * n + (t & 1)] : 0.f;
        }
        __syncthreads();

        int cnt = nEnd - c0; if (cnt > CHUNK) cnt = CHUNK;
#pragma unroll 4
        for (int n = 0; n < cnt; ++n) {
            const float4 a4 = *(const float4*)(As + n * TILE + tx * 4);
            const float4 b4 = *(const float4*)(Bs + n * TILE + ty * 4);
            const v2f y01 = *(const v2f*)(Ys + 2 * n);
            float av[4] = {a4.x, a4.y, a4.z, a4.w};
            v2f bp[2]; bp[0] = (v2f){b4.x, b4.y}; bp[1] = (v2f){b4.z, b4.w};
#pragma unroll
            for (int di = 0; di < 4; ++di)
#pragma unroll
                for (int djp = 0; djp < 2; ++djp) {
                    v2f w2 = av[di] * bp[djp];            // v_pk_mul_f32
                    accW[di * 2 + djp] += w2;             // v_pk_add_f32
                    accPQ[di * 4 + djp * 2]     += w2.x * y01;  // v_pk_fma_f32
                    accPQ[di * 4 + djp * 2 + 1] += w2.y * y01;  // v_pk_fma_f32
                }
        }
    }

    // unpack accumulators to [di][dj] scalars
    float wv[4][4], pv[4][4], qv[4][4];
#pragma unroll
    for (int di = 0; di < 4; ++di)
#pragma unroll
        for (int dj = 0; dj < 4; ++dj) {
            wv[di][dj] = accW[di * 2 + (dj >> 1)][dj & 1];
            pv[di][dj] = accPQ[di * 4 + dj].x;
            qv[di][dj] = accPQ[di * 4 + dj].y;
        }

    if (mode == 0) {
        const size_t cstride = (size_t)nslice * NG;
        float* pw = dst + (size_t)slice * NG;
#pragma unroll
        for (int dj = 0; dj < 4; ++dj) {
            int gj = tJ + ty * 4 + dj;
            int gp = gj * NXA + tI + tx * 4;     // j-major, 4 consecutive gi
            float4 w4 = make_float4(wv[0][dj], wv[1][dj], wv[2][dj], wv[3][dj]);
            float4 p4 = make_float4(pv[0][dj], pv[1][dj], pv[2][dj], pv[3][dj]);
            float4 q4 = make_float4(qv[0][dj], qv[1][dj], qv[2][dj], qv[3][dj]);
            *(float4*)(pw + gp)               = w4;
            *(float4*)(pw + cstride + gp)     = p4;
            *(float4*)(pw + 2 * cstride + gp) = q4;
        }
    } else {
#pragma unroll
        for (int di = 0; di < 4; ++di) {
            int gi = tI + tx * 4 + di;
#pragma unroll
            for (int dj = 0; dj < 4; ++dj) {
                int gj = tJ + ty * 4 + dj;
                int o  = gj * NXA + gi;          // out[c][j][i]
                atomicAdd(dst + 0 * NG + o, wv[di][dj]);
                atomicAdd(dst + 1 * NG + o, pv[di][dj]);
                atomicAdd(dst + 2 * NG + o, qv[di][dj]);
            }
        }
    }
}

// reduce nslice partials, normalize, write (already in out layout g' = j*128+i).
// 256 blocks x 256 thr; block owns 64 consecutive g'; thread = (q, slice-group).
__global__ __launch_bounds__(256) void k_reduce_norm(const float* __restrict__ fm,
                                                     float* __restrict__ out,
                                                     int nslice) {
    __shared__ v4f sAcc[3][16][16];          // [ch][sgrp][q] : 12 KB
    const int q  = threadIdx.x & 15;         // float4 column within block's 64 g'
    const int sg = threadIdx.x >> 4;         // 16 slice groups
    const int gp = blockIdx.x * 64 + q * 4;
    const size_t cstride = (size_t)nslice * NG;
    const int per = nslice >> 4;             // nslice is 64/128/256 -> /16 exact
    v4f w = (v4f)(0.f), p = (v4f)(0.f), qv = (v4f)(0.f);
    int s0 = sg * per, s1 = s0 + per;
    for (int s = s0; s < s1; ++s) {
        const float* base = fm + (size_t)s * NG + gp;    // coalesced float4
        w  += *(const v4f*)(base);
        p  += *(const v4f*)(base + cstride);
        qv += *(const v4f*)(base + 2 * cstride);
    }
    sAcc[0][sg][q] = w; sAcc[1][sg][q] = p; sAcc[2][sg][q] = qv;
    __syncthreads();
    if (threadIdx.x < 16) {
        const int qq = threadIdx.x;
        v4f W = (v4f)(0.f), P = (v4f)(0.f), Q = (v4f)(0.f);
#pragma unroll
        for (int s = 0; s < 16; ++s) {
            W += sAcc[0][s][qq]; P += sAcc[1][s][qq]; Q += sAcc[2][s][qq];
        }
        v4f inv; inv.x = 1.f / W.x; inv.y = 1.f / W.y;
        inv.z = 1.f / W.z; inv.w = 1.f / W.w;
        const int o = blockIdx.x * 64 + qq * 4;
        *(v4f*)(out + o)          = W;
        *(v4f*)(out + NG + o)     = P * inv;
        *(v4f*)(out + 2 * NG + o) = Q * inv;
    }
}

// atomic path: normalize in place (density already in channel 0)
__global__ __launch_bounds__(256) void k_norm_inplace(float* __restrict__ out) {
    int t = blockIdx.x * 256 + threadIdx.x;
    if (t >= NG) return;
    float inv = 1.f / out[t];
    out[NG + t]     *= inv;
    out[2 * NG + t] *= inv;
}

extern "C" void kernel_launch(void* const* d_in, const int* in_sizes, int n_in,
                              void* d_out, int out_size, void* d_ws, size_t ws_size,
                              hipStream_t stream) {
    const float* X = (const float*)d_in[0];
    const float* Y = (const float*)d_in[1];
    float* out = (float*)d_out;
    const size_t per_slice = (size_t)NG * 3 * sizeof(float);   // 196.6 KB

    int nslice = 0;
    if      (ws_size >= 256 * per_slice) nslice = 256;  // 50.3 MB
    else if (ws_size >= 128 * per_slice) nslice = 128;  // 25.2 MB
    else if (ws_size >=  64 * per_slice) nslice = 64;   // 12.6 MB

    if (nslice > 0) {
        int slice_len = (NC + nslice - 1) / nslice;
        float* fm = (float*)d_ws;
        dim3 grid(4, nslice);
        k_accum<<<grid, 256, 0, stream>>>(X, Y, fm, nslice, slice_len, 0);
        k_reduce_norm<<<NG / 64, 256, 0, stream>>>(fm, out, nslice);
    } else {
        hipMemsetAsync(d_out, 0, (size_t)out_size * sizeof(float), stream);
        dim3 grid(4, 64);
        k_accum<<<grid, 256, 0, stream>>>(X, Y, out, 64, (NC + 63) / 64, 1);
        k_norm_inplace<<<(NG + 255) / 256, 256, 0, stream>>>(out);
    }
}

// Round 4
// 78.931 us; speedup vs baseline: 1.5079x; 1.2948x over previous
//
#include <hip/hip_runtime.h>

// Steerable_Encoder: separable Gaussian KDE onto a 128x128 grid.
// FM[i,j,c] = sum_n A[i,n]*B[j,n]*EY[n,c]  ->  f16 MFMA GEMM, transposed:
// D[j, (c,i)] = sum_n Bgauss[j,n] * (Agauss[i,n]*EY[n,c]),  K = 20000.
// R4: 32x32x16 f16 MFMA, nslice=128 split-K partials (25 MB), reduce+norm.

#define NXA 128
#define NG  16384
#define NC  20000
#define KC  32            // ctx per staged chunk (2 MFMA k-steps of 16)
#define LDA 34            // f16 row stride: 68 B = 17 banks, coprime 32
#define NSL 128           // split-K slices
#define SLEN 157          // ceil(20000/128)

#define STEP (20.0f / 127.0f)
#define KNEG (-0.72134752044448170368f)    // -0.5 * log2(e)

typedef _Float16 v8h  __attribute__((ext_vector_type(8)));
typedef float    v16f __attribute__((ext_vector_type(16)));
typedef float    v4f  __attribute__((ext_vector_type(4)));

__device__ __forceinline__ float fast_exp2(float x) {
    return __builtin_amdgcn_exp2f(x);
}

// Block: grid-j strip of 32 (position p) x all 384 (c,i) cols, one K-slice.
// Wave w covers n-cols [96w, 96w+96) as 3 tiles of 32x32.
__global__ __launch_bounds__(256) void k_mfma(const float* __restrict__ X,
                                              const float* __restrict__ Y,
                                              float* __restrict__ fm) {
    __shared__ _Float16 Ag[32 * LDA];     // j-gaussian rows   [32][KC]
    __shared__ _Float16 Bm[384 * LDA];    // (c,i) rows: e, e*y0, e*y1
    __shared__ float    Xs[KC * 2];
    __shared__ float    Ys[KC * 2];

    const int t     = threadIdx.x;
    const int p     = blockIdx.x;         // 0..3 : gj base = 32p
    const int slice = blockIdx.y;         // 0..NSL-1
    const int n0    = slice * SLEN;
    int nEnd = n0 + SLEN; if (nEnd > NC) nEnd = NC;

    const int lane = t & 63, wave = t >> 6;
    const int l31 = lane & 31, lh = lane >> 5;

    v16f acc[3];
#pragma unroll
    for (int m = 0; m < 3; ++m) acc[m] = (v16f)(0.f);

    for (int c0 = n0; c0 < nEnd; c0 += KC) {
        __syncthreads();
        // stage ctx coords: OOB -> x sentinel 1e19 (dx^2=1e38 finite, exp2->0)
        if (t < KC) {
            int n = c0 + t;
            float2 xv = (n < NC) ? *(const float2*)(X + 2 * n)
                                 : make_float2(1e19f, 1e19f);
            float2 yv = (n < NC) ? *(const float2*)(Y + 2 * n)
                                 : make_float2(0.f, 0.f);
            if (n >= nEnd) { xv = make_float2(1e19f, 1e19f); yv = make_float2(0.f, 0.f); }
            Xs[2 * t] = xv.x; Xs[2 * t + 1] = xv.y;
            Ys[2 * t] = yv.x; Ys[2 * t + 1] = yv.y;
        }
        __syncthreads();

        // stage Bm rows (c,i): thread = (i0 = t>>2, kgroup = t&3), 2 passes
        {
            const int kg = t & 3;
            const int i0 = t >> 2;
            const float* xp = Xs + kg * 16;   // x pairs for n = c0+kg*8+u
            const float* yp = Ys + kg * 16;
#pragma unroll
            for (int pass = 0; pass < 2; ++pass) {
                int i = i0 + 64 * pass;
                float gx = -10.f + (float)i * STEP;
                v8h e, e1, e2;
#pragma unroll
                for (int u = 0; u < 8; ++u) {
                    float dx = gx - xp[2 * u];
                    float w  = fast_exp2(dx * dx * KNEG);
                    e[u]  = (_Float16)w;
                    e1[u] = (_Float16)(w * yp[2 * u]);
                    e2[u] = (_Float16)(w * yp[2 * u + 1]);
                }
                *(v8h*)(Bm + i * LDA + kg * 8)         = e;
                *(v8h*)(Bm + (128 + i) * LDA + kg * 8) = e1;
                *(v8h*)(Bm + (256 + i) * LDA + kg * 8) = e2;
            }
        }
        // stage Ag rows (j): 32 rows x 4 kgroups = 128 tasks
        if (t < 128) {
            const int kg = t & 3;
            const int j  = t >> 2;
            float gy = 10.f - (float)(32 * p + j) * STEP;
            const float* xp = Xs + kg * 16;
            v8h e;
#pragma unroll
            for (int u = 0; u < 8; ++u) {
                float dy = gy - xp[2 * u + 1];
                e[u] = (_Float16)fast_exp2(dy * dy * KNEG);
            }
            *(v8h*)(Ag + j * LDA + kg * 8) = e;
        }
        __syncthreads();

        // 2 k-steps x 3 tiles of v_mfma_f32_32x32x16_f16
#pragma unroll
        for (int s = 0; s < 2; ++s) {
            int k = s * 16 + lh * 8;
            v8h af = *(const v8h*)(Ag + l31 * LDA + k);
#pragma unroll
            for (int tn = 0; tn < 3; ++tn) {
                int n = wave * 96 + tn * 32 + l31;
                v8h bf = *(const v8h*)(Bm + n * LDA + k);
                acc[tn] = __builtin_amdgcn_mfma_f32_32x32x16_f16(af, bf, acc[tn], 0, 0, 0);
            }
        }
    }

    // epilogue: D[row=j][col=(c,i)] -> fm[c][slice][gj*128 + i], coalesced in i
    const size_t cstride = (size_t)NSL * NG;
#pragma unroll
    for (int tn = 0; tn < 3; ++tn) {
        int n = wave * 96 + tn * 32 + l31;
        int c = n >> 7, i = n & 127;
        float* base = fm + (size_t)c * cstride + (size_t)slice * NG + i;
#pragma unroll
        for (int r = 0; r < 16; ++r) {
            int j  = (r & 3) + 8 * (r >> 2) + 4 * lh;
            int gj = 32 * p + j;
            base[gj * NXA] = acc[tn][r];
        }
    }
}

// reduce nslice partials, normalize, write (g' = j*128+i = out layout).
__global__ __launch_bounds__(256) void k_reduce_norm(const float* __restrict__ fm,
                                                     float* __restrict__ out,
                                                     int nslice) {
    __shared__ v4f sAcc[3][16][16];
    const int q  = threadIdx.x & 15;
    const int sg = threadIdx.x >> 4;
    const int gp = blockIdx.x * 64 + q * 4;
    const size_t cstride = (size_t)nslice * NG;
    const int per = nslice >> 4;
    v4f w = (v4f)(0.f), pp = (v4f)(0.f), qq = (v4f)(0.f);
    int s0 = sg * per, s1 = s0 + per;
    for (int s = s0; s < s1; ++s) {
        const float* base = fm + (size_t)s * NG + gp;
        w  += *(const v4f*)(base);
        pp += *(const v4f*)(base + cstride);
        qq += *(const v4f*)(base + 2 * cstride);
    }
    sAcc[0][sg][q] = w; sAcc[1][sg][q] = pp; sAcc[2][sg][q] = qq;
    __syncthreads();
    if (threadIdx.x < 16) {
        const int c = threadIdx.x;
        v4f W = (v4f)(0.f), P = (v4f)(0.f), Q = (v4f)(0.f);
#pragma unroll
        for (int s = 0; s < 16; ++s) {
            W += sAcc[0][s][c]; P += sAcc[1][s][c]; Q += sAcc[2][s][c];
        }
        v4f inv; inv.x = 1.f / W.x; inv.y = 1.f / W.y;
        inv.z = 1.f / W.z; inv.w = 1.f / W.w;
        const int o = blockIdx.x * 64 + c * 4;
        *(v4f*)(out + o)          = W;
        *(v4f*)(out + NG + o)     = P * inv;
        *(v4f*)(out + 2 * NG + o) = Q * inv;
    }
}

// ---- fallback (tiny ws): fp32 atomic path, known-correct ----
__global__ __launch_bounds__(256) void k_accum_atomic(const float* __restrict__ X,
                                                      const float* __restrict__ Y,
                                                      float* __restrict__ dst,
                                                      int slice_len) {
    __shared__ float As[64 * 64], Bs[64 * 64], Yl[64 * 2];
    const int t = threadIdx.x, tx = t & 15, ty = t >> 4;
    const int pos = blockIdx.x;
    const int tI = (pos >> 1) * 64, tJ = (pos & 1) * 64;
    const int n0 = blockIdx.y * slice_len;
    int nEnd = n0 + slice_len; if (nEnd > NC) nEnd = NC;
    float aw[16], ap[16], aq[16];
#pragma unroll
    for (int k = 0; k < 16; ++k) { aw[k] = ap[k] = aq[k] = 0.f; }
    for (int c0 = n0; c0 < nEnd; c0 += 64) {
        __syncthreads();
#pragma unroll
        for (int k = 0; k < 16; ++k) {
            int l = k * 256 + t, nl = l >> 6, ii = l & 63, n = c0 + nl;
            float a = 0.f, b = 0.f;
            if (n < nEnd) {
                float dx = (-10.f + (float)(tI + ii) * STEP) - X[2 * n];
                float dy = (10.f - (float)(tJ + ii) * STEP) - X[2 * n + 1];
                a = fast_exp2(dx * dx * KNEG);
                b = fast_exp2(dy * dy * KNEG);
            }
            As[nl * 64 + ii] = a; Bs[nl * 64 + ii] = b;
        }
        if (t < 128) { int n = c0 + (t >> 1); Yl[t] = (n < nEnd) ? Y[2 * n + (t & 1)] : 0.f; }
        __syncthreads();
        int cnt = nEnd - c0; if (cnt > 64) cnt = 64;
        for (int n = 0; n < cnt; ++n) {
            const float4 a4 = *(const float4*)(As + n * 64 + tx * 4);
            const float4 b4 = *(const float4*)(Bs + n * 64 + ty * 4);
            float y0 = Yl[2 * n], y1 = Yl[2 * n + 1];
            float av[4] = {a4.x, a4.y, a4.z, a4.w};
            float bv[4] = {b4.x, b4.y, b4.z, b4.w};
#pragma unroll
            for (int di = 0; di < 4; ++di)
#pragma unroll
                for (int dj = 0; dj < 4; ++dj) {
                    int k = di * 4 + dj;
                    float w = av[di] * bv[dj];
                    aw[k] += w; ap[k] = fmaf(w, y0, ap[k]); aq[k] = fmaf(w, y1, aq[k]);
                }
        }
    }
#pragma unroll
    for (int di = 0; di < 4; ++di)
#pragma unroll
        for (int dj = 0; dj < 4; ++dj) {
            int gi = tI + tx * 4 + di, gj = tJ + ty * 4 + dj;
            int o = gj * NXA + gi, k = di * 4 + dj;
            atomicAdd(dst + o, aw[k]);
            atomicAdd(dst + NG + o, ap[k]);
            atomicAdd(dst + 2 * NG + o, aq[k]);
        }
}

__global__ __launch_bounds__(256) void k_norm_inplace(float* __restrict__ out) {
    int t = blockIdx.x * 256 + threadIdx.x;
    if (t >= NG) return;
    float inv = 1.f / out[t];
    out[NG + t] *= inv; out[2 * NG + t] *= inv;
}

extern "C" void kernel_launch(void* const* d_in, const int* in_sizes, int n_in,
                              void* d_out, int out_size, void* d_ws, size_t ws_size,
                              hipStream_t stream) {
    const float* X = (const float*)d_in[0];
    const float* Y = (const float*)d_in[1];
    float* out = (float*)d_out;
    const size_t need = (size_t)NSL * NG * 3 * sizeof(float);   // 25.2 MB
    if (ws_size >= need) {
        float* fm = (float*)d_ws;
        k_mfma<<<dim3(4, NSL), 256, 0, stream>>>(X, Y, fm);
        k_reduce_norm<<<NG / 64, 256, 0, stream>>>(fm, out, NSL);
    } else {
        hipMemsetAsync(d_out, 0, (size_t)out_size * sizeof(float), stream);
        k_accum_atomic<<<dim3(4, 64), 256, 0, stream>>>(X, Y, out, (NC + 63) / 64);
        k_norm_inplace<<<(NG + 255) / 256, 256, 0, stream>>>(out);
    }
}

// Round 5
// 76.448 us; speedup vs baseline: 1.5569x; 1.0325x over previous
//
#include <hip/hip_runtime.h>

// Steerable_Encoder: separable Gaussian KDE onto a 128x128 grid.
// FM[i,j,c] = sum_n A[i,n]*B[j,n]*EY[n,c]  ->  f16 MFMA GEMM, transposed:
// D[j, (c,i)] = sum_n Bgauss[j,n] * (Agauss[i,n]*EY[n,c]),  K = 20000.
// R5: nslice=125 (slen=160 = 5*KC exact, no masks), no Xs LDS stage
// (global float4 X/Y reads, L1-hot, register prefetch), 2 barriers/chunk,
// parallel 512-block reduce. Partials fm[c][slice][g'] = 24.6 MB in ws.

#define NXA 128
#define NG  16384
#define NC  20000
#define KC  32            // ctx per staged chunk (2 MFMA k-steps of 16)
#define LDA 34            // f16 row stride: 68 B = 17 banks, coprime 32
#define NSL 125           // split-K slices: 125 * 160 = 20000 exactly
#define SLEN 160
#define NCHUNK 5          // SLEN / KC

#define STEP (20.0f / 127.0f)
#define KNEG (-0.72134752044448170368f)    // -0.5 * log2(e)

typedef _Float16 v8h  __attribute__((ext_vector_type(8)));
typedef float    v16f __attribute__((ext_vector_type(16)));
typedef float    v4f  __attribute__((ext_vector_type(4)));

__device__ __forceinline__ float fast_exp2(float x) {
    return __builtin_amdgcn_exp2f(x);
}

// Block: grid-j strip of 32 (position p) x all 384 (c,i) cols, one K-slice.
// Wave w covers n-cols [96w, 96w+96) as 3 tiles of 32x32.
__global__ __launch_bounds__(256) void k_mfma(const float* __restrict__ X,
                                              const float* __restrict__ Y,
                                              float* __restrict__ fm) {
    __shared__ _Float16 Ag[32 * LDA];     // j-gaussian rows   [32][KC]
    __shared__ _Float16 Bm[384 * LDA];    // (c,i) rows: e, e*y0, e*y1

    const int t     = threadIdx.x;
    const int p     = blockIdx.x;         // 0..3 : gj base = 32p
    const int slice = blockIdx.y;         // 0..NSL-1
    const int n0    = slice * SLEN;

    const int lane = t & 63, wave = t >> 6;
    const int l31 = lane & 31, lh = lane >> 5;
    const int kg = t & 3;                 // k-group: points kg*8..kg*8+7
    const int i0 = t >> 2;                // Bm row (pass 0); +64 for pass 1
    const float gx0 = -10.f + (float)i0 * STEP;
    const float gx1 = -10.f + (float)(i0 + 64) * STEP;
    const float gyj = 10.f - (float)(32 * p + (t >> 2)) * STEP;  // for t<128

    const float4* Xp = (const float4*)X;  // float4 f covers points 2f, 2f+1
    const float4* Yp = (const float4*)Y;
    const int fb0 = (n0 >> 1) + kg * 4;   // this thread's float4 base

    v16f acc[3];
#pragma unroll
    for (int m = 0; m < 3; ++m) acc[m] = (v16f)(0.f);

    // prefetch chunk 0
    float4 xf[4], yf[4];
#pragma unroll
    for (int q = 0; q < 4; ++q) { xf[q] = Xp[fb0 + q]; yf[q] = Yp[fb0 + q]; }

#pragma unroll
    for (int m = 0; m < NCHUNK; ++m) {
        float4 xc[4], yc[4];
#pragma unroll
        for (int q = 0; q < 4; ++q) { xc[q] = xf[q]; yc[q] = yf[q]; }

        __syncthreads();                  // prev chunk's MFMA reads done

        if (m < NCHUNK - 1) {             // issue next chunk's loads early
            int fb = fb0 + 16 * (m + 1);
#pragma unroll
            for (int q = 0; q < 4; ++q) { xf[q] = Xp[fb + q]; yf[q] = Yp[fb + q]; }
        }

        // ---- stage Bm rows (c,i): 2 passes of 128 i, 8 k each ----
        {
            float xu[8], y0u[8], y1u[8];
#pragma unroll
            for (int q = 0; q < 4; ++q) {
                xu[2 * q]      = xc[q].x;  xu[2 * q + 1]  = xc[q].z;
                y0u[2 * q]     = yc[q].x;  y0u[2 * q + 1] = yc[q].z;
                y1u[2 * q]     = yc[q].y;  y1u[2 * q + 1] = yc[q].w;
            }
            v8h e, e1, e2;
#pragma unroll
            for (int u = 0; u < 8; ++u) {
                float dx = gx0 - xu[u];
                float w  = fast_exp2(dx * dx * KNEG);
                e[u]  = (_Float16)w;
                e1[u] = (_Float16)(w * y0u[u]);
                e2[u] = (_Float16)(w * y1u[u]);
            }
            *(v8h*)(Bm + i0 * LDA + kg * 8)         = e;
            *(v8h*)(Bm + (128 + i0) * LDA + kg * 8) = e1;
            *(v8h*)(Bm + (256 + i0) * LDA + kg * 8) = e2;
#pragma unroll
            for (int u = 0; u < 8; ++u) {
                float dx = gx1 - xu[u];
                float w  = fast_exp2(dx * dx * KNEG);
                e[u]  = (_Float16)w;
                e1[u] = (_Float16)(w * y0u[u]);
                e2[u] = (_Float16)(w * y1u[u]);
            }
            *(v8h*)(Bm + (64 + i0) * LDA + kg * 8)  = e;
            *(v8h*)(Bm + (192 + i0) * LDA + kg * 8) = e1;
            *(v8h*)(Bm + (320 + i0) * LDA + kg * 8) = e2;
        }
        // ---- stage Ag rows (j): waves 0-1 only ----
        if (t < 128) {
            v8h a;
#pragma unroll
            for (int u = 0; u < 8; ++u) {
                float x1u = (u & 1) ? ((u >> 1) == 0 ? xc[0].w : (u >> 1) == 1 ? xc[1].w : (u >> 1) == 2 ? xc[2].w : xc[3].w)
                                    : ((u >> 1) == 0 ? xc[0].y : (u >> 1) == 1 ? xc[1].y : (u >> 1) == 2 ? xc[2].y : xc[3].y);
                float dy = gyj - x1u;
                a[u] = (_Float16)fast_exp2(dy * dy * KNEG);
            }
            *(v8h*)(Ag + (t >> 2) * LDA + kg * 8) = a;
        }
        __syncthreads();

        // ---- 2 k-steps x 3 tiles of v_mfma_f32_32x32x16_f16 ----
#pragma unroll
        for (int s = 0; s < 2; ++s) {
            int k = s * 16 + lh * 8;
            v8h af = *(const v8h*)(Ag + l31 * LDA + k);
#pragma unroll
            for (int tn = 0; tn < 3; ++tn) {
                int n = wave * 96 + tn * 32 + l31;
                v8h bf = *(const v8h*)(Bm + n * LDA + k);
                acc[tn] = __builtin_amdgcn_mfma_f32_32x32x16_f16(af, bf, acc[tn], 0, 0, 0);
            }
        }
    }

    // epilogue: D[row=j][col=(c,i)] -> fm[c][slice][gj*128 + i], contiguous in i
    const size_t cstride = (size_t)NSL * NG;
#pragma unroll
    for (int tn = 0; tn < 3; ++tn) {
        int n = wave * 96 + tn * 32 + l31;
        int c = n >> 7, i = n & 127;
        float* base = fm + (size_t)c * cstride + (size_t)slice * NG + i;
#pragma unroll
        for (int r = 0; r < 16; ++r) {
            int j  = (r & 3) + 8 * (r >> 2) + 4 * lh;
            int gj = 32 * p + j;
            base[gj * NXA] = acc[tn][r];
        }
    }
}

// reduce NSL partials, normalize, write (g' = j*128+i = out layout).
// 512 blocks x 256 thr; block owns 32 g'; thread = (q in 0..7, sg in 0..31).
__global__ __launch_bounds__(256) void k_reduce_norm(const float* __restrict__ fm,
                                                     float* __restrict__ out) {
    __shared__ v4f sAcc[3][32][8];        // 12 KB
    const int q  = threadIdx.x & 7;
    const int sg = threadIdx.x >> 3;
    const int gp = blockIdx.x * 32 + q * 4;
    const size_t cstride = (size_t)NSL * NG;
    const int per = (NSL + 31) >> 5;      // 4
    int s0 = sg * per;
    int s1 = s0 + per; if (s1 > NSL) s1 = NSL;
    v4f w = (v4f)(0.f), pp = (v4f)(0.f), qq = (v4f)(0.f);
    for (int s = s0; s < s1; ++s) {
        const float* base = fm + (size_t)s * NG + gp;
        w  += *(const v4f*)(base);
        pp += *(const v4f*)(base + cstride);
        qq += *(const v4f*)(base + 2 * cstride);
    }
    sAcc[0][sg][q] = w; sAcc[1][sg][q] = pp; sAcc[2][sg][q] = qq;
    __syncthreads();
    if (threadIdx.x < 8) {
        const int c = threadIdx.x;
        v4f W = (v4f)(0.f), P = (v4f)(0.f), Q = (v4f)(0.f);
#pragma unroll
        for (int s = 0; s < 32; ++s) {
            W += sAcc[0][s][c]; P += sAcc[1][s][c]; Q += sAcc[2][s][c];
        }
        v4f inv; inv.x = 1.f / W.x; inv.y = 1.f / W.y;
        inv.z = 1.f / W.z; inv.w = 1.f / W.w;
        const int o = blockIdx.x * 32 + c * 4;
        *(v4f*)(out + o)          = W;
        *(v4f*)(out + NG + o)     = P * inv;
        *(v4f*)(out + 2 * NG + o) = Q * inv;
    }
}

// ---- fallback (tiny ws): fp32 atomic path, known-correct ----
__global__ __launch_bounds__(256) void k_accum_atomic(const float* __restrict__ X,
                                                      const float* __restrict__ Y,
                                                      float* __restrict__ dst,
                                                      int slice_len) {
    __shared__ float As[64 * 64], Bs[64 * 64], Yl[64 * 2];
    const int t = threadIdx.x, tx = t & 15, ty = t >> 4;
    const int pos = blockIdx.x;
    const int tI = (pos >> 1) * 64, tJ = (pos & 1) * 64;
    const int n0 = blockIdx.y * slice_len;
    int nEnd = n0 + slice_len; if (nEnd > NC) nEnd = NC;
    float aw[16], ap[16], aq[16];
#pragma unroll
    for (int k = 0; k < 16; ++k) { aw[k] = ap[k] = aq[k] = 0.f; }
    for (int c0 = n0; c0 < nEnd; c0 += 64) {
        __syncthreads();
#pragma unroll
        for (int k = 0; k < 16; ++k) {
            int l = k * 256 + t, nl = l >> 6, ii = l & 63, n = c0 + nl;
            float a = 0.f, b = 0.f;
            if (n < nEnd) {
                float dx = (-10.f + (float)(tI + ii) * STEP) - X[2 * n];
                float dy = (10.f - (float)(tJ + ii) * STEP) - X[2 * n + 1];
                a = fast_exp2(dx * dx * KNEG);
                b = fast_exp2(dy * dy * KNEG);
            }
            As[nl * 64 + ii] = a; Bs[nl * 64 + ii] = b;
        }
        if (t < 128) { int n = c0 + (t >> 1); Yl[t] = (n < nEnd) ? Y[2 * n + (t & 1)] : 0.f; }
        __syncthreads();
        int cnt = nEnd - c0; if (cnt > 64) cnt = 64;
        for (int n = 0; n < cnt; ++n) {
            const float4 a4 = *(const float4*)(As + n * 64 + tx * 4);
            const float4 b4 = *(const float4*)(Bs + n * 64 + ty * 4);
            float y0 = Yl[2 * n], y1 = Yl[2 * n + 1];
            float av[4] = {a4.x, a4.y, a4.z, a4.w};
            float bv[4] = {b4.x, b4.y, b4.z, b4.w};
#pragma unroll
            for (int di = 0; di < 4; ++di)
#pragma unroll
                for (int dj = 0; dj < 4; ++dj) {
                    int k = di * 4 + dj;
                    float w = av[di] * bv[dj];
                    aw[k] += w; ap[k] = fmaf(w, y0, ap[k]); aq[k] = fmaf(w, y1, aq[k]);
                }
        }
    }
#pragma unroll
    for (int di = 0; di < 4; ++di)
#pragma unroll
        for (int dj = 0; dj < 4; ++dj) {
            int gi = tI + tx * 4 + di, gj = tJ + ty * 4 + dj;
            int o = gj * NXA + gi, k = di * 4 + dj;
            atomicAdd(dst + o, aw[k]);
            atomicAdd(dst + NG + o, ap[k]);
            atomicAdd(dst + 2 * NG + o, aq[k]);
        }
}

__global__ __launch_bounds__(256) void k_norm_inplace(float* __restrict__ out) {
    int t = blockIdx.x * 256 + threadIdx.x;
    if (t >= NG) return;
    float inv = 1.f / out[t];
    out[NG + t] *= inv; out[2 * NG + t] *= inv;
}

extern "C" void kernel_launch(void* const* d_in, const int* in_sizes, int n_in,
                              void* d_out, int out_size, void* d_ws, size_t ws_size,
                              hipStream_t stream) {
    const float* X = (const float*)d_in[0];
    const float* Y = (const float*)d_in[1];
    float* out = (float*)d_out;
    const size_t need = (size_t)NSL * NG * 3 * sizeof(float);   // 24.6 MB
    if (ws_size >= need) {
        float* fm = (float*)d_ws;
        k_mfma<<<dim3(4, NSL), 256, 0, stream>>>(X, Y, fm);
        k_reduce_norm<<<NG / 32, 256, 0, stream>>>(fm, out);
    } else {
        hipMemsetAsync(d_out, 0, (size_t)out_size * sizeof(float), stream);
        k_accum_atomic<<<dim3(4, 64), 256, 0, stream>>>(X, Y, out, (NC + 63) / 64);
        k_norm_inplace<<<(NG + 255) / 256, 256, 0, stream>>>(out);
    }
}